// Round 1
// baseline (261.331 us; speedup 1.0000x reference)
//
#include <hip/hip_runtime.h>
#include <cfloat>
#include <cmath>

#define DEVINL __device__ __forceinline__

constexpr int N_ = 4, C_ = 21, H_ = 512, W_ = 512;
constexpr int P_ = 171;           // pooled H/W: floor((512+2-3)/3)+1
constexpr int Q_ = 169;           // point grid: P-3+1
constexpr int NC_ = N_ * C_;      // 84
constexpr int HW_ = H_ * W_;
constexpr int PP_ = P_ * P_;
constexpr int NCOV_ = 189;        // 9 + 9 + 45 + 45 + 81
constexpr float EPS_ = 5e-4f;

// triangular packed index: entry (d,e) with d<=e at tstart(d)+(e-d)
DEVINL constexpr int tstart(int d) { return d * 9 - d * (d - 1) / 2; }

DEVINL float wave_sum(float v) {
#pragma unroll
    for (int o = 32; o > 0; o >>= 1) v += __shfl_down(v, o, 64);
    return v;
}

// ---------------------------------------------------------------------------
// Kernel 1: fused CE + sigmoid/clip + 3x3/s3 max-pool of probs and onehot.
// One thread per pooled cell (n,i,j); stride==kernel => disjoint windows.
// ---------------------------------------------------------------------------
__global__ __launch_bounds__(256) void k_fused(const float* __restrict__ score,
                                               const int* __restrict__ target,
                                               float* __restrict__ pr,
                                               float* __restrict__ la,
                                               float* __restrict__ cov_ce) {
    int gid = blockIdx.x * 256 + threadIdx.x;
    float nll = 0.f, cnt = 0.f;
    if (gid < N_ * PP_) {
        int j = gid % P_;
        int i = (gid / P_) % P_;
        int n = gid / PP_;
        float prmax[C_];
#pragma unroll
        for (int c = 0; c < C_; ++c) prmax[c] = -FLT_MAX;
        unsigned lamask = 0;
        const float* sbase = score + (size_t)n * C_ * HW_;
        const int* tbase = target + (size_t)n * HW_;
        int h0 = 3 * i - 1, w0 = 3 * j - 1;
#pragma unroll
        for (int dy = 0; dy < 3; ++dy) {
            int h = h0 + dy;
            if (h < 0 || h >= H_) continue;
#pragma unroll
            for (int dx = 0; dx < 3; ++dx) {
                int w = w0 + dx;
                if (w < 0 || w >= W_) continue;
                int t = tbase[h * W_ + w];
                const float* sp = sbase + h * W_ + w;
                float s[C_];
#pragma unroll
                for (int c = 0; c < C_; ++c) s[c] = sp[(size_t)c * HW_];
                // ---- cross entropy (log-softmax over C) ----
                float m = s[0];
#pragma unroll
                for (int c = 1; c < C_; ++c) m = fmaxf(m, s[c]);
                float se = 0.f;
#pragma unroll
                for (int c = 0; c < C_; ++c) se += __expf(s[c] - m);
                float lse = m + __logf(se);
                if (t != 255) {
                    int tc = (t >= 0 && t < C_) ? t : 0;
                    nll += (lse - s[tc]);
                    cnt += 1.f;
                }
                // ---- onehot + masked sigmoid probs, pooled max ----
                bool maskv = (t >= 0 && t < C_);
                if (maskv) lamask |= (1u << t);
                float mf = maskv ? 1.f : 0.f;
#pragma unroll
                for (int c = 0; c < C_; ++c) {
                    float p = mf * __builtin_amdgcn_rcpf(1.f + __expf(-s[c]));
                    p = fminf(fmaxf(p, 1e-6f), 1.f);
                    prmax[c] = fmaxf(prmax[c], p);
                }
            }
        }
        size_t ob = (size_t)n * C_ * PP_ + (size_t)i * P_ + j;
#pragma unroll
        for (int c = 0; c < C_; ++c) {
            pr[ob + (size_t)c * PP_] = prmax[c];
            la[ob + (size_t)c * PP_] = ((lamask >> c) & 1u) ? 1.f : 0.f;
        }
    }
    // CE block reduction -> global atomics (cov_ce[NC_*NCOV_ + {0,1}])
    nll = wave_sum(nll);
    cnt = wave_sum(cnt);
    if ((threadIdx.x & 63) == 0) {
        atomicAdd(&cov_ce[NC_ * NCOV_ + 0], nll);
        atomicAdd(&cov_ce[NC_ * NCOV_ + 1], cnt);
    }
}

// ---------------------------------------------------------------------------
// Kernel 2: raw covariance sums per (n,c). Point (i,j) in [0,169)^2 reads the
// 3x3 neighborhood of la/pr; accumulate 189 sums in registers, reduce via
// wave shuffles + LDS, one atomicAdd set per block.
// grid = (84, 6 row-chunks), block = 256
// ---------------------------------------------------------------------------
__global__ __launch_bounds__(256, 2) void k_cov(const float* __restrict__ la,
                                                const float* __restrict__ pr,
                                                float* __restrict__ cov) {
    int nc = blockIdx.x;
    int chunk = blockIdx.y;
    const float* A = la + (size_t)nc * PP_;
    const float* B = pr + (size_t)nc * PP_;
    constexpr int RC = 29;  // ceil(169/6)
    int r0 = chunk * RC;
    int rend = r0 + RC;
    if (rend > Q_) rend = Q_;
    int npts = (rend - r0) * Q_;

    float sA[9], sB[9], SAA[45], SBB[45], SAB[81];
#pragma unroll
    for (int k = 0; k < 9; ++k) { sA[k] = 0.f; sB[k] = 0.f; }
#pragma unroll
    for (int k = 0; k < 45; ++k) { SAA[k] = 0.f; SBB[k] = 0.f; }
#pragma unroll
    for (int k = 0; k < 81; ++k) SAB[k] = 0.f;

    for (int idx = threadIdx.x; idx < npts; idx += 256) {
        int lr = idx / Q_;
        int col = idx - lr * Q_;
        int row = r0 + lr;
        const float* ap = A + row * P_ + col;
        const float* bp = B + row * P_ + col;
        float a[9], b[9];
#pragma unroll
        for (int dy = 0; dy < 3; ++dy)
#pragma unroll
            for (int dx = 0; dx < 3; ++dx) {
                a[dy * 3 + dx] = ap[dy * P_ + dx];
                b[dy * 3 + dx] = bp[dy * P_ + dx];
            }
#pragma unroll
        for (int d = 0; d < 9; ++d) { sA[d] += a[d]; sB[d] += b[d]; }
        {
            int k = 0;
#pragma unroll
            for (int d = 0; d < 9; ++d)
#pragma unroll
                for (int e = d; e < 9; ++e) {
                    SAA[k] += a[d] * a[e];
                    SBB[k] += b[d] * b[e];
                    ++k;
                }
        }
#pragma unroll
        for (int d = 0; d < 9; ++d)
#pragma unroll
            for (int e = 0; e < 9; ++e) SAB[d * 9 + e] += a[d] * b[e];
    }

    __shared__ float red[4][NCOV_];
    int lane = threadIdx.x & 63;
    int wv = threadIdx.x >> 6;
#pragma unroll
    for (int d = 0; d < 9; ++d) { float v = wave_sum(sA[d]); if (lane == 0) red[wv][d] = v; }
#pragma unroll
    for (int d = 0; d < 9; ++d) { float v = wave_sum(sB[d]); if (lane == 0) red[wv][9 + d] = v; }
#pragma unroll
    for (int k = 0; k < 45; ++k) { float v = wave_sum(SAA[k]); if (lane == 0) red[wv][18 + k] = v; }
#pragma unroll
    for (int k = 0; k < 45; ++k) { float v = wave_sum(SBB[k]); if (lane == 0) red[wv][63 + k] = v; }
#pragma unroll
    for (int k = 0; k < 81; ++k) { float v = wave_sum(SAB[k]); if (lane == 0) red[wv][108 + k] = v; }
    __syncthreads();
    for (int k = threadIdx.x; k < NCOV_; k += 256) {
        float v = red[0][k] + red[1][k] + red[2][k] + red[3][k];
        atomicAdd(&cov[nc * NCOV_ + k], v);
    }
}

// ---------------------------------------------------------------------------
// Kernel 3: per-(n,c) 9x9 algebra (fully unrolled, triangular packed) + final
// combine. One block of 128 threads; thread t<84 handles pair t.
// ---------------------------------------------------------------------------
__global__ __launch_bounds__(128) void k_final(const float* __restrict__ cov,
                                               float* __restrict__ out) {
    __shared__ float red[128];
    int t = threadIdx.x;
    float my = 0.f;
    if (t < NC_) {
        const float* S = cov + t * NCOV_;
        const float Lf = (float)(Q_ * Q_);  // 28561
        float sA[9], sB[9];
#pragma unroll
        for (int d = 0; d < 9; ++d) { sA[d] = S[d]; sB[d] = S[9 + d]; }
        float laC[45], M[45], Cm[81];
        {
            int k = 0;
#pragma unroll
            for (int d = 0; d < 9; ++d)
#pragma unroll
                for (int e = d; e < 9; ++e) {
                    laC[k] = S[18 + k] - sA[d] * sA[e] / Lf;
                    M[k] = S[63 + k] - sB[d] * sB[e] / Lf + (d == e ? EPS_ : 0.f);
                    ++k;
                }
#pragma unroll
            for (int d = 0; d < 9; ++d)
#pragma unroll
                for (int e = 0; e < 9; ++e)
                    Cm[d * 9 + e] = S[108 + d * 9 + e] - sA[d] * sB[e] / Lf;
        }
        // Cholesky of M in place: L(i,j) at M[tstart(j)+(i-j)], i>=j
#pragma unroll
        for (int j = 0; j < 9; ++j) {
            float s = M[tstart(j)];
#pragma unroll
            for (int k = 0; k < j; ++k) { float l = M[tstart(k) + (j - k)]; s -= l * l; }
            float dj = sqrtf(fmaxf(s, 1e-30f));
            M[tstart(j)] = dj;
            float inv = 1.f / dj;
#pragma unroll
            for (int i = j + 1; i < 9; ++i) {
                float s2 = M[tstart(j) + (i - j)];
#pragma unroll
                for (int k = 0; k < j; ++k)
                    s2 -= M[tstart(k) + (i - k)] * M[tstart(k) + (j - k)];
                M[tstart(j) + (i - j)] = s2 * inv;
            }
        }
        // Forward solve Y = L^{-1} C^T in place on Cm (row p becomes y-vector)
#pragma unroll
        for (int p = 0; p < 9; ++p) {
#pragma unroll
            for (int i = 0; i < 9; ++i) {
                float s = Cm[p * 9 + i];
#pragma unroll
                for (int k = 0; k < i; ++k)
                    s -= M[tstart(k) + (i - k)] * Cm[p * 9 + k];
                Cm[p * 9 + i] = s / M[tstart(i)];
            }
        }
        // A = la_cov - Y^T Y + eps I, in place on laC
#pragma unroll
        for (int d = 0; d < 9; ++d)
#pragma unroll
            for (int e = d; e < 9; ++e) {
                float s = 0.f;
#pragma unroll
                for (int i = 0; i < 9; ++i) s += Cm[d * 9 + i] * Cm[e * 9 + i];
                laC[tstart(d) + (e - d)] -= s;
                if (d == e) laC[tstart(d)] += EPS_;
            }
        // Cholesky of A, rmi = sum log(diag + 1e-8)
        float rmi = 0.f;
#pragma unroll
        for (int j = 0; j < 9; ++j) {
            float s = laC[tstart(j)];
#pragma unroll
            for (int k = 0; k < j; ++k) { float l = laC[tstart(k) + (j - k)]; s -= l * l; }
            float dj = sqrtf(fmaxf(s, 0.f));
            laC[tstart(j)] = dj;
            float inv = 1.f / fmaxf(dj, 1e-30f);
#pragma unroll
            for (int i = j + 1; i < 9; ++i) {
                float s2 = laC[tstart(j) + (i - j)];
#pragma unroll
                for (int k = 0; k < j; ++k)
                    s2 -= laC[tstart(k) + (i - k)] * laC[tstart(k) + (j - k)];
                laC[tstart(j) + (i - j)] = s2 * inv;
            }
            rmi += __logf(dj + 1e-8f);
        }
        my = rmi;
    }
    red[t] = my;
    __syncthreads();
#pragma unroll
    for (int o = 64; o > 0; o >>= 1) {
        if (t < o) red[t] += red[t + o];
        __syncthreads();
    }
    if (t == 0) {
        float rmi_total = red[0] / 36.f;  // / (N * HALF_D)
        float ce = cov[NC_ * NCOV_ + 0] / cov[NC_ * NCOV_ + 1];
        out[0] = 0.5f * ce + 0.5f * rmi_total;
    }
}

extern "C" void kernel_launch(void* const* d_in, const int* in_sizes, int n_in,
                              void* d_out, int out_size, void* d_ws, size_t ws_size,
                              hipStream_t stream) {
    const float* score = (const float*)d_in[0];
    const int* target = (const int*)d_in[1];
    float* pr = (float*)d_ws;
    float* la = pr + (size_t)NC_ * PP_;
    float* cov = la + (size_t)NC_ * PP_;  // NC_*NCOV_ sums + 2 CE floats
    hipMemsetAsync(cov, 0, (size_t)(NC_ * NCOV_ + 2) * sizeof(float), stream);

    int nthreads = N_ * PP_;
    k_fused<<<dim3((nthreads + 255) / 256), dim3(256), 0, stream>>>(score, target, pr, la, cov);
    dim3 g2(NC_, 6);
    k_cov<<<g2, dim3(256), 0, stream>>>(la, pr, cov);
    k_final<<<dim3(1), dim3(128), 0, stream>>>(cov, (float*)d_out);
}